// Round 5
// baseline (116.213 us; speedup 1.0000x reference)
//
#include <hip/hip_runtime.h>
#include <hip/hip_bf16.h>

typedef short short8 __attribute__((ext_vector_type(8)));
typedef float f32x4 __attribute__((ext_vector_type(4)));
typedef float f32x16 __attribute__((ext_vector_type(16)));
typedef __hip_bfloat16 bf16;

// Problem constants: B=2, S=2048, D=1024, H=16, HD=64, SCALE=1/8

__device__ __forceinline__ void glds16(const void* g, void* l) {
  __builtin_amdgcn_global_load_lds((const __attribute__((address_space(1))) unsigned int*)g,
                                   (__attribute__((address_space(3))) unsigned int*)l, 16, 0, 0);
}

// ---------------------------------------------------------------- cvt src
__global__ __launch_bounds__(256) void cvt_src_kernel(const float4* __restrict__ in,
                                                      bf16* __restrict__ out, int n4) {
  int i = blockIdx.x * 256 + threadIdx.x;
  if (i >= n4) return;
  float4 v = in[i];
  union { bf16 h[4]; uint2 u; } pk;
  pk.h[0] = __float2bfloat16(v.x);
  pk.h[1] = __float2bfloat16(v.y);
  pk.h[2] = __float2bfloat16(v.z);
  pk.h[3] = __float2bfloat16(v.w);
  *(uint2*)(out + (size_t)i * 4) = pk.u;
}

// ------------------------------------------------- transpose w -> bf16 B^T
__global__ __launch_bounds__(256) void transpose_w_kernel(const float* __restrict__ w,
                                                          bf16* __restrict__ wt) {
  __shared__ float tile[32][33];
  int x0 = blockIdx.x * 32;
  int y0 = blockIdx.y * 32;
  int tx = threadIdx.x & 31, ty = threadIdx.x >> 5;
#pragma unroll
  for (int i = 0; i < 4; i++) {
    int y = ty + i * 8;
    tile[y][tx] = w[(size_t)(y0 + y) * 3072 + x0 + tx];
  }
  __syncthreads();
#pragma unroll
  for (int i = 0; i < 4; i++) {
    int y = ty + i * 8;
    wt[(size_t)(x0 + y) * 1024 + y0 + tx] = __float2bfloat16(tile[tx][y]);
  }
}

// ------------------------------------------------------------ QKV GEMM v2 (unchanged)
__global__ __launch_bounds__(256) void qkv_gemm_kernel(
    const bf16* __restrict__ A, const bf16* __restrict__ Bt,
    const float* __restrict__ bias,
    bf16* __restrict__ q_ws, bf16* __restrict__ k_ws, bf16* __restrict__ vt_ws) {
  __shared__ alignas(16) char AB[32768];  // As [0,16K), Bs [16K,32K)
  const int tid = threadIdx.x;
  const int lane = tid & 63, wid = tid >> 6;
  const int lr = lane & 15, lg = lane >> 4;
  const int wm = wid >> 1, wn = wid & 1;
  const int m0 = blockIdx.x * 128, n0 = blockIdx.y * 128;

  const f32x4 z4 = {0.f, 0.f, 0.f, 0.f};
  f32x4 acc[4][4];
#pragma unroll
  for (int m = 0; m < 4; m++)
#pragma unroll
    for (int n = 0; n < 4; n++) acc[m][n] = z4;

  const int srow = lane >> 3;
  const int sseg = (lane & 7) ^ srow;
  const char* Ag = (const char*)A + (size_t)(m0 + wid * 32 + srow) * 2048 + sseg * 16;
  const char* Bg = (const char*)Bt + (size_t)(n0 + wid * 32 + srow) * 2048 + sseg * 16;
  char* Al = AB + wid * 4096;
  char* Bl = AB + 16384 + wid * 4096;
  const int xora = (lr & 7) << 4;

  for (int kt = 0; kt < 16; kt++) {
    __syncthreads();
#pragma unroll
    for (int c = 0; c < 4; c++) {
      glds16(Ag + (size_t)kt * 128 + c * 16384, Al + c * 1024);
      glds16(Bg + (size_t)kt * 128 + c * 16384, Bl + c * 1024);
    }
    asm volatile("s_waitcnt vmcnt(0)" ::: "memory");
    __syncthreads();
#pragma unroll
    for (int g = 0; g < 2; g++) {
      short8 af[4], bfr[4];
#pragma unroll
      for (int m = 0; m < 4; m++)
        af[m] = *(const short8*)(AB + (wm * 64 + m * 16 + lr) * 128 +
                                 ((g * 64 + lg * 16) ^ xora));
#pragma unroll
      for (int n = 0; n < 4; n++)
        bfr[n] = *(const short8*)(AB + 16384 + (wn * 64 + n * 16 + lr) * 128 +
                                  ((g * 64 + lg * 16) ^ xora));
#pragma unroll
      for (int m = 0; m < 4; m++)
#pragma unroll
        for (int n = 0; n < 4; n++)
          acc[m][n] = __builtin_amdgcn_mfma_f32_16x16x32_bf16(af[m], bfr[n], acc[m][n], 0, 0, 0);
    }
  }

  const int which = n0 >> 10;
#pragma unroll
  for (int m = 0; m < 4; m++) {
    int row = m0 + wm * 64 + m * 16 + lg * 4;
    int b = row >> 11;
    int ss0 = row & 2047;
#pragma unroll
    for (int n = 0; n < 4; n++) {
      int col = n0 + wn * 64 + n * 16 + lr;
      int d = col & 1023;
      int h = d >> 6, hd = d & 63;
      size_t bh = (size_t)(b * 16 + h);
      float bv = bias[col];
      if (which == 2) {
        union { bf16 h4[4]; uint2 u; } pk;
#pragma unroll
        for (int r = 0; r < 4; r++) pk.h4[r] = __float2bfloat16(acc[m][n][r] + bv);
        *(uint2*)&vt_ws[(bh * 64 + hd) * 2048 + ss0] = pk.u;
      } else {
        bf16* dst = (which == 0) ? q_ws : k_ws;
#pragma unroll
        for (int r = 0; r < 4; r++)
          dst[(bh * 2048 + (ss0 + r)) * 64 + hd] = __float2bfloat16(acc[m][n][r] + bv);
      }
    }
  }
}

// ------------------------------------------------------------ attention v5
// Split-K flash-decode: 512 blocks (ks in {0,1} handles keys [ks*1024, ks*1024+1024)),
// 8 waves x 32 q each. Emits unnormalized partial O (f32) + (m,l) per q-row.
// Compute body identical to verified round-4 kernel (scale folded into exp2 fma).
__global__ __launch_bounds__(512) void attn2_kernel(
    const bf16* __restrict__ q_ws, const bf16* __restrict__ k_ws,
    const bf16* __restrict__ vt_ws, float* __restrict__ po, float* __restrict__ ml) {
  __shared__ alignas(16) char smem[65536];
  const int tid = threadIdx.x;
  const int lane = tid & 63, wid = tid >> 6;
  const int lq = lane & 31, hi = lane >> 5;
  const int hi16 = hi * 16;
  const int xorv = (lq & 7) << 4;
  const float scale_l2e = 0.125f * 1.44269504088896f;

  // decode: ks pairs adjacent (same XCD sees both halves of a bh -> Q/L2 reuse)
  const int f = blockIdx.x;
  const int ks = f & 1;
  const int g = f >> 1;
  const int bh = (g & 7) * 4 + ((g >> 3) & 3);
  const int qb = g >> 5;
  const int q0 = qb * 256 + wid * 32;

  short8 qf[4];
  {
    const bf16* qrow = q_ws + ((size_t)bh * 2048 + q0 + lq) * 64;
#pragma unroll
    for (int s = 0; s < 4; s++) qf[s] = *(const short8*)(qrow + s * 16 + hi * 8);
  }

  const int seg = (lane & 7) ^ (lane >> 3);
  const char* kgl = (const char*)k_ws + (size_t)bh * 2048 * 128 + (size_t)ks * 16 * 8192 +
                    (size_t)(wid * 8 + (lane >> 3)) * 128 + seg * 16;
  const char* vgl = (const char*)vt_ws + (size_t)bh * 64 * 4096 + ks * 2048 +
                    (size_t)(wid * 8 + (lane >> 3)) * 4096 + seg * 16;

  f32x16 o0, o1;
#pragma unroll
  for (int r = 0; r < 16; r++) { o0[r] = 0.f; o1[r] = 0.f; }
  float m = -1e30f, l = 0.f;

#pragma unroll
  for (int p = 0; p < 3; p++) {
    glds16(kgl + (size_t)p * 8192, smem + p * 8192 + wid * 1024);
    glds16(vgl + (size_t)p * 128, smem + 32768 + p * 8192 + wid * 1024);
  }
  asm volatile("s_waitcnt vmcnt(4)" ::: "memory");
  __builtin_amdgcn_s_barrier();

  for (int kt = 0; kt < 16; ++kt) {
    const int buf = kt & 3;
    if (kt + 3 < 16) {
      glds16(kgl + (size_t)(kt + 3) * 8192, smem + ((kt + 3) & 3) * 8192 + wid * 1024);
      glds16(vgl + (size_t)(kt + 3) * 128, smem + 32768 + ((kt + 3) & 3) * 8192 + wid * 1024);
    }
    const int curK = buf * 8192;
    const int curV = 32768 + buf * 8192;

    // ---- S^T = K * Q^T ----
    f32x16 s0, s1;
#pragma unroll
    for (int r = 0; r < 16; r++) { s0[r] = 0.f; s1[r] = 0.f; }
#pragma unroll
    for (int s = 0; s < 4; s++) {
      const int doff = (s * 32 + hi16) ^ xorv;
      short8 k0 = *(const short8*)(smem + curK + lq * 128 + doff);
      short8 k1 = *(const short8*)(smem + curK + 4096 + lq * 128 + doff);
      __builtin_amdgcn_s_setprio(1);
      s0 = __builtin_amdgcn_mfma_f32_32x32x16_bf16(k0, qf[s], s0, 0, 0, 0);
      s1 = __builtin_amdgcn_mfma_f32_32x32x16_bf16(k1, qf[s], s1, 0, 0, 0);
      __builtin_amdgcn_s_setprio(0);
    }

    // ---- softmax (raw-domain max tree; scale folded into exp2 fma) ----
    float mx[8];
#pragma unroll
    for (int i = 0; i < 8; i++) mx[i] = fmaxf(fmaxf(s0[i], s0[i + 8]), fmaxf(s1[i], s1[i + 8]));
#pragma unroll
    for (int i = 0; i < 4; i++) mx[i] = fmaxf(mx[i], mx[i + 4]);
    float pm = fmaxf(fmaxf(mx[0], mx[1]), fmaxf(mx[2], mx[3]));
    pm = fmaxf(pm, __shfl_xor(pm, 32));
    pm *= scale_l2e;
    if (pm > m + 8.f) {  // defer-max (T13)
      float rs = __builtin_amdgcn_exp2f(m - pm);
      m = pm; l *= rs;
#pragma unroll
      for (int r = 0; r < 16; r++) { o0[r] *= rs; o1[r] *= rs; }
    }
    float sum[8];
#pragma unroll
    for (int r = 0; r < 16; r++) {
      s0[r] = __builtin_amdgcn_exp2f(__builtin_fmaf(s0[r], scale_l2e, -m));
      s1[r] = __builtin_amdgcn_exp2f(__builtin_fmaf(s1[r], scale_l2e, -m));
    }
#pragma unroll
    for (int i = 0; i < 8; i++) sum[i] = (s0[i] + s0[i + 8]) + (s1[i] + s1[i + 8]);
#pragma unroll
    for (int i = 0; i < 4; i++) sum[i] += sum[i + 4];
    float ps = (sum[0] + sum[1]) + (sum[2] + sum[3]);
    ps += __shfl_xor(ps, 32);
    l += ps;

    // ---- O^T += V^T * P^T ----
#pragma unroll
    for (int kb = 0; kb < 2; kb++) {
      uint w[8], t[8];
#pragma unroll
      for (int i = 0; i < 8; i++) {
        union { bf16 h2[2]; uint u; } pk;
        float plo = kb ? s1[2 * i] : s0[2 * i];
        float phi = kb ? s1[2 * i + 1] : s0[2 * i + 1];
        pk.h2[0] = __float2bfloat16(plo);
        pk.h2[1] = __float2bfloat16(phi);
        w[i] = pk.u;
      }
#pragma unroll
      for (int i = 0; i < 8; i++) t[i] = (uint)__shfl_xor((int)w[i], 32);
      union { uint u[4]; short8 s; } ua, ub;
      ua.u[0] = hi ? t[2] : w[0];
      ua.u[1] = hi ? t[3] : w[1];
      ua.u[2] = hi ? w[2] : t[0];
      ua.u[3] = hi ? w[3] : t[1];
      ub.u[0] = hi ? t[6] : w[4];
      ub.u[1] = hi ? t[7] : w[5];
      ub.u[2] = hi ? w[6] : t[4];
      ub.u[3] = hi ? w[7] : t[5];
#pragma unroll
      for (int s = 0; s < 2; s++) {
        short8 pa = s ? ub.s : ua.s;
        const int koff = (kb * 64 + s * 32 + hi16) ^ xorv;
        short8 v0 = *(const short8*)(smem + curV + lq * 128 + koff);
        short8 v1 = *(const short8*)(smem + curV + 4096 + lq * 128 + koff);
        __builtin_amdgcn_s_setprio(1);
        o0 = __builtin_amdgcn_mfma_f32_32x32x16_bf16(v0, pa, o0, 0, 0, 0);
        o1 = __builtin_amdgcn_mfma_f32_32x32x16_bf16(v1, pa, o1, 0, 0, 0);
        __builtin_amdgcn_s_setprio(0);
      }
    }

    if (kt < 13)       asm volatile("s_waitcnt vmcnt(4)" ::: "memory");
    else if (kt == 13) asm volatile("s_waitcnt vmcnt(2)" ::: "memory");
    else if (kt == 14) asm volatile("s_waitcnt vmcnt(0)" ::: "memory");
    if (kt < 15) __builtin_amdgcn_s_barrier();
  }
  __syncthreads();

  // ---- epilogue: write (m,l) + unnormalized partial O via rotated LDS ----
  if (hi == 0) {
    float2 v = {m, l};
    *(float2*)&ml[((size_t)(ks * 32 + bh) * 2048 + q0 + lq) * 2] = v;
  }
  float* ep = (float*)(smem) + wid * 1024;
  const int eq = lane >> 1, eds = lane & 1;
  float* pobase = po + ((size_t)(ks * 32 + bh) * 2048 + q0 + eq) * 64 + eds * 16;
#pragma unroll
  for (int db = 0; db < 2; db++) {
#pragma unroll
    for (int r = 0; r < 16; r++) {
      int d = (r & 3) + 8 * (r >> 2) + 4 * hi;
      float v = (db ? o1[r] : o0[r]);
      ep[lq * 32 + ((d + lq) & 31)] = v;
    }
#pragma unroll
    for (int c = 0; c < 4; c++) {
      float4 t;
      t.x = ep[eq * 32 + ((eds * 16 + 4 * c + 0 + eq) & 31)];
      t.y = ep[eq * 32 + ((eds * 16 + 4 * c + 1 + eq) & 31)];
      t.z = ep[eq * 32 + ((eds * 16 + 4 * c + 2 + eq) & 31)];
      t.w = ep[eq * 32 + ((eds * 16 + 4 * c + 3 + eq) & 31)];
      *(float4*)(pobase + db * 32 + 4 * c) = t;
    }
  }
}

// ------------------------------------------------------------ merge halves
__global__ __launch_bounds__(256) void merge_kernel(const float* __restrict__ po,
                                                    const float* __restrict__ ml,
                                                    float* __restrict__ out) {
  int i = blockIdx.x * 256 + threadIdx.x;  // float4 index, 1048576 total
  int c4 = i & 255;                        // 256 float4 per (b,s) row
  int bs = i >> 8;                         // b*2048 + s
  int h = c4 >> 4, hd4 = c4 & 15;
  int b = bs >> 11, s = bs & 2047;
  size_t row0 = (size_t)(b * 16 + h) * 2048 + s;
  size_t row1 = (size_t)(32 + b * 16 + h) * 2048 + s;
  float2 ml0 = *(const float2*)&ml[row0 * 2];
  float2 ml1 = *(const float2*)&ml[row1 * 2];
  float M = fmaxf(ml0.x, ml1.x);
  float w0 = __builtin_amdgcn_exp2f(ml0.x - M);
  float w1 = __builtin_amdgcn_exp2f(ml1.x - M);
  float inv = 1.f / (ml0.y * w0 + ml1.y * w1);
  w0 *= inv; w1 *= inv;
  float4 a = *(const float4*)&po[row0 * 64 + hd4 * 4];
  float4 c = *(const float4*)&po[row1 * 64 + hd4 * 4];
  float4 r;
  r.x = a.x * w0 + c.x * w1;
  r.y = a.y * w0 + c.y * w1;
  r.z = a.z * w0 + c.z * w1;
  r.w = a.w * w0 + c.w * w1;
  *(float4*)&out[(size_t)bs * 1024 + c4 * 4] = r;
}

// ---------------------------------------------------------------- launch
extern "C" void kernel_launch(void* const* d_in, const int* in_sizes, int n_in,
                              void* d_out, int out_size, void* d_ws, size_t ws_size,
                              hipStream_t stream) {
  (void)in_sizes; (void)n_in; (void)out_size; (void)ws_size;
  const float* src  = (const float*)d_in[0];
  const float* w    = (const float*)d_in[1];
  const float* bias = (const float*)d_in[2];
  float* out = (float*)d_out;

  // ws layout (60 MB):
  //   [0, 33.5M):      po  f32 [2][32][2048][64]   (aliases src_bf/wt_bf, disjoint in time)
  //   [33.5M, 34.6M):  ml  f32 [2][32][2048][2]
  //   [34.6M, 59.8M):  q_ws / k_ws / vt_ws  bf16
  char* ws = (char*)d_ws;
  float* po = (float*)ws;
  float* ml = (float*)(ws + 33554432);
  bf16* src_bf = (bf16*)ws;                   // dead before attn writes po
  bf16* wt_bf  = (bf16*)(ws + 8388608);
  bf16* q_ws   = (bf16*)(ws + 34603008);
  bf16* k_ws   = q_ws + 4194304;
  bf16* vt_ws  = k_ws + 4194304;

  cvt_src_kernel<<<4096, 256, 0, stream>>>((const float4*)src, src_bf, 1048576);
  transpose_w_kernel<<<dim3(96, 32), 256, 0, stream>>>(w, wt_bf);
  qkv_gemm_kernel<<<dim3(32, 24), 256, 0, stream>>>(src_bf, wt_bf, bias, q_ws, k_ws, vt_ws);
  attn2_kernel<<<512, 512, 0, stream>>>(q_ws, k_ws, vt_ws, po, ml);
  merge_kernel<<<4096, 256, 0, stream>>>(po, ml, out);
}

// Round 6
// 102.693 us; speedup vs baseline: 1.1316x; 1.1316x over previous
//
#include <hip/hip_runtime.h>
#include <hip/hip_bf16.h>

typedef short short8 __attribute__((ext_vector_type(8)));
typedef float f32x4 __attribute__((ext_vector_type(4)));
typedef float f32x16 __attribute__((ext_vector_type(16)));
typedef __hip_bfloat16 bf16;

// Problem constants: B=2, S=2048, D=1024, H=16, HD=64, SCALE=1/8

__device__ __forceinline__ void glds16(const void* g, void* l) {
  __builtin_amdgcn_global_load_lds((const __attribute__((address_space(1))) unsigned int*)g,
                                   (__attribute__((address_space(3))) unsigned int*)l, 16, 0, 0);
}

__device__ __forceinline__ uint pk2(float a, float b) {
  union { bf16 h2[2]; uint u; } pk;
  pk.h2[0] = __float2bfloat16(a);
  pk.h2[1] = __float2bfloat16(b);
  return pk.u;
}

// ---------------------------------------------------------------- cvt src
__global__ __launch_bounds__(256) void cvt_src_kernel(const float4* __restrict__ in,
                                                      bf16* __restrict__ out, int n4) {
  int i = blockIdx.x * 256 + threadIdx.x;
  if (i >= n4) return;
  float4 v = in[i];
  union { bf16 h[4]; uint2 u; } pk;
  pk.h[0] = __float2bfloat16(v.x);
  pk.h[1] = __float2bfloat16(v.y);
  pk.h[2] = __float2bfloat16(v.z);
  pk.h[3] = __float2bfloat16(v.w);
  *(uint2*)(out + (size_t)i * 4) = pk.u;
}

// ------------------------------------------------- transpose w -> bf16 B^T
__global__ __launch_bounds__(256) void transpose_w_kernel(const float* __restrict__ w,
                                                          bf16* __restrict__ wt) {
  __shared__ float tile[32][33];
  int x0 = blockIdx.x * 32;
  int y0 = blockIdx.y * 32;
  int tx = threadIdx.x & 31, ty = threadIdx.x >> 5;
#pragma unroll
  for (int i = 0; i < 4; i++) {
    int y = ty + i * 8;
    tile[y][tx] = w[(size_t)(y0 + y) * 3072 + x0 + tx];
  }
  __syncthreads();
#pragma unroll
  for (int i = 0; i < 4; i++) {
    int y = ty + i * 8;
    wt[(size_t)(x0 + y) * 1024 + y0 + tx] = __float2bfloat16(tile[tx][y]);
  }
}

// ------------------------------------------------------------ QKV GEMM v2 (unchanged)
__global__ __launch_bounds__(256) void qkv_gemm_kernel(
    const bf16* __restrict__ A, const bf16* __restrict__ Bt,
    const float* __restrict__ bias,
    bf16* __restrict__ q_ws, bf16* __restrict__ k_ws, bf16* __restrict__ vt_ws) {
  __shared__ alignas(16) char AB[32768];  // As [0,16K), Bs [16K,32K)
  const int tid = threadIdx.x;
  const int lane = tid & 63, wid = tid >> 6;
  const int lr = lane & 15, lg = lane >> 4;
  const int wm = wid >> 1, wn = wid & 1;
  const int m0 = blockIdx.x * 128, n0 = blockIdx.y * 128;

  const f32x4 z4 = {0.f, 0.f, 0.f, 0.f};
  f32x4 acc[4][4];
#pragma unroll
  for (int m = 0; m < 4; m++)
#pragma unroll
    for (int n = 0; n < 4; n++) acc[m][n] = z4;

  const int srow = lane >> 3;
  const int sseg = (lane & 7) ^ srow;
  const char* Ag = (const char*)A + (size_t)(m0 + wid * 32 + srow) * 2048 + sseg * 16;
  const char* Bg = (const char*)Bt + (size_t)(n0 + wid * 32 + srow) * 2048 + sseg * 16;
  char* Al = AB + wid * 4096;
  char* Bl = AB + 16384 + wid * 4096;
  const int xora = (lr & 7) << 4;

  for (int kt = 0; kt < 16; kt++) {
    __syncthreads();
#pragma unroll
    for (int c = 0; c < 4; c++) {
      glds16(Ag + (size_t)kt * 128 + c * 16384, Al + c * 1024);
      glds16(Bg + (size_t)kt * 128 + c * 16384, Bl + c * 1024);
    }
    asm volatile("s_waitcnt vmcnt(0)" ::: "memory");
    __syncthreads();
#pragma unroll
    for (int g = 0; g < 2; g++) {
      short8 af[4], bfr[4];
#pragma unroll
      for (int m = 0; m < 4; m++)
        af[m] = *(const short8*)(AB + (wm * 64 + m * 16 + lr) * 128 +
                                 ((g * 64 + lg * 16) ^ xora));
#pragma unroll
      for (int n = 0; n < 4; n++)
        bfr[n] = *(const short8*)(AB + 16384 + (wn * 64 + n * 16 + lr) * 128 +
                                  ((g * 64 + lg * 16) ^ xora));
#pragma unroll
      for (int m = 0; m < 4; m++)
#pragma unroll
        for (int n = 0; n < 4; n++)
          acc[m][n] = __builtin_amdgcn_mfma_f32_16x16x32_bf16(af[m], bfr[n], acc[m][n], 0, 0, 0);
    }
  }

  const int which = n0 >> 10;
#pragma unroll
  for (int m = 0; m < 4; m++) {
    int row = m0 + wm * 64 + m * 16 + lg * 4;
    int b = row >> 11;
    int ss0 = row & 2047;
#pragma unroll
    for (int n = 0; n < 4; n++) {
      int col = n0 + wn * 64 + n * 16 + lr;
      int d = col & 1023;
      int h = d >> 6, hd = d & 63;
      size_t bh = (size_t)(b * 16 + h);
      float bv = bias[col];
      if (which == 2) {
        union { bf16 h4[4]; uint2 u; } pk;
#pragma unroll
        for (int r = 0; r < 4; r++) pk.h4[r] = __float2bfloat16(acc[m][n][r] + bv);
        *(uint2*)&vt_ws[(bh * 64 + hd) * 2048 + ss0] = pk.u;
      } else {
        bf16* dst = (which == 0) ? q_ws : k_ws;
#pragma unroll
        for (int r = 0; r < 4; r++)
          dst[(bh * 2048 + (ss0 + r)) * 64 + hd] = __float2bfloat16(acc[m][n][r] + bv);
      }
    }
  }
}

// ------------------------------------------------------------ attention v6
// Single-pass, 256 blocks x 8 waves x 32 q. KVBLK=128: one softmax/pack pass
// per 128 keys (4 independent QK chains s0..s3, 4 split PV accumulators),
// halved barriers, halved exchange shfls. Double-buffered 32KB K+V tiles.
__global__ __launch_bounds__(512) void attn3_kernel(
    const bf16* __restrict__ q_ws, const bf16* __restrict__ k_ws,
    const bf16* __restrict__ vt_ws, float* __restrict__ out) {
  // [0,32K): K bufs [2][128][64] bf16 (row&7 xor-swz); [32K,64K): V^T bufs
  // [2][64][128] bf16 (256B rows, chunk ^ (d&15) swz)
  __shared__ alignas(16) char smem[65536];
  const int tid = threadIdx.x;
  const int lane = tid & 63, wid = tid >> 6;
  const int lq = lane & 31, hi = lane >> 5;
  const int hi16 = hi * 16;
  const int xorv = (lq & 7) << 4;
  const float scale_l2e = 0.125f * 1.44269504088896f;

  // XCD-grouped decode (round-4 mapping, verified)
  const int f = blockIdx.x;
  const int bh = (f & 7) * 4 + ((f >> 3) & 3);
  const int qb = f >> 5;
  const int b = bh >> 4, h = bh & 15;
  const int q0 = qb * 256 + wid * 32;

  short8 qf[4];
  {
    const bf16* qrow = q_ws + ((size_t)bh * 2048 + q0 + lq) * 64;
#pragma unroll
    for (int s = 0; s < 4; s++) qf[s] = *(const short8*)(qrow + s * 16 + hi * 8);
  }

  // --- staging addresses ---
  // K: wave w stages tile rows w*16 + c*8 + (lane>>3); row&7 == lane>>3
  const int l8 = lane >> 3;
  const int segk = (lane & 7) ^ l8;
  const char* kgl = (const char*)k_ws + (size_t)bh * 262144 +
                    (size_t)(wid * 16 + l8) * 128 + segk * 16;
  // V^T: wave w stages chunks {2w, 2w+1}; chunk c' covers d rows c'*4 + (lane>>4)
  const int l16 = lane >> 4;
  const int d0v = (wid * 2 + 0) * 4 + l16;
  const int d1v = (wid * 2 + 1) * 4 + l16;
  const char* vg0 = (const char*)vt_ws + (size_t)bh * 262144 + (size_t)d0v * 4096 +
                    (((lane & 15) ^ (d0v & 15)) << 4);
  const char* vg1 = (const char*)vt_ws + (size_t)bh * 262144 + (size_t)d1v * 4096 +
                    (((lane & 15) ^ (d1v & 15)) << 4);

  f32x16 o0a, o0b, o1a, o1b;
#pragma unroll
  for (int r = 0; r < 16; r++) { o0a[r] = 0.f; o0b[r] = 0.f; o1a[r] = 0.f; o1b[r] = 0.f; }
  float m = -1e30f, l = 0.f;

  // prologue: stage tile 0 into buf 0
  glds16(kgl, smem + wid * 2048);
  glds16(kgl + 1024, smem + wid * 2048 + 1024);
  glds16(vg0, smem + 32768 + wid * 2048);
  glds16(vg1, smem + 32768 + wid * 2048 + 1024);
  asm volatile("s_waitcnt vmcnt(0)" ::: "memory");
  __builtin_amdgcn_s_barrier();

  for (int kt = 0; kt < 16; ++kt) {
    const int kb_off = (kt & 1) * 16384;
    const int vb_off = 32768 + (kt & 1) * 16384;
    if (kt + 1 < 16) {  // issue next tile into other buffer; lands under compute
      const int nb = ((kt + 1) & 1) * 16384;
      glds16(kgl + (size_t)(kt + 1) * 16384, smem + nb + wid * 2048);
      glds16(kgl + (size_t)(kt + 1) * 16384 + 1024, smem + nb + wid * 2048 + 1024);
      glds16(vg0 + (size_t)(kt + 1) * 256, smem + 32768 + nb + wid * 2048);
      glds16(vg1 + (size_t)(kt + 1) * 256, smem + 32768 + nb + wid * 2048 + 1024);
    }

    // ---- S^T = K * Q^T : 4 independent 4-deep chains over 128 keys ----
    f32x16 s0, s1, s2, s3;
#pragma unroll
    for (int r = 0; r < 16; r++) { s0[r] = 0.f; s1[r] = 0.f; s2[r] = 0.f; s3[r] = 0.f; }
#pragma unroll
    for (int st = 0; st < 4; st++) {
      const int doff = (st * 32 + hi16) ^ xorv;
      short8 ka = *(const short8*)(smem + kb_off + lq * 128 + doff);
      short8 kb = *(const short8*)(smem + kb_off + (lq + 32) * 128 + doff);
      short8 kc = *(const short8*)(smem + kb_off + (lq + 64) * 128 + doff);
      short8 kd = *(const short8*)(smem + kb_off + (lq + 96) * 128 + doff);
      __builtin_amdgcn_s_setprio(1);
      s0 = __builtin_amdgcn_mfma_f32_32x32x16_bf16(ka, qf[st], s0, 0, 0, 0);
      s1 = __builtin_amdgcn_mfma_f32_32x32x16_bf16(kb, qf[st], s1, 0, 0, 0);
      s2 = __builtin_amdgcn_mfma_f32_32x32x16_bf16(kc, qf[st], s2, 0, 0, 0);
      s3 = __builtin_amdgcn_mfma_f32_32x32x16_bf16(kd, qf[st], s3, 0, 0, 0);
      __builtin_amdgcn_s_setprio(0);
    }

    // ---- softmax over 128 keys (lane pair (lq,hi) shares row q=lq) ----
    float mx[16];
#pragma unroll
    for (int i = 0; i < 16; i++)
      mx[i] = fmaxf(fmaxf(s0[i], s1[i]), fmaxf(s2[i], s3[i]));
#pragma unroll
    for (int i = 0; i < 8; i++) mx[i] = fmaxf(mx[i], mx[i + 8]);
#pragma unroll
    for (int i = 0; i < 4; i++) mx[i] = fmaxf(mx[i], mx[i + 4]);
    float pm = fmaxf(fmaxf(mx[0], mx[1]), fmaxf(mx[2], mx[3]));
    pm = fmaxf(pm, __shfl_xor(pm, 32));
    pm *= scale_l2e;
    if (pm > m + 8.f) {  // defer-max (T13)
      float rs = __builtin_amdgcn_exp2f(m - pm);
      m = pm; l *= rs;
#pragma unroll
      for (int r = 0; r < 16; r++) {
        o0a[r] *= rs; o0b[r] *= rs; o1a[r] *= rs; o1b[r] *= rs;
      }
    }
#pragma unroll
    for (int r = 0; r < 16; r++) {
      s0[r] = __builtin_amdgcn_exp2f(__builtin_fmaf(s0[r], scale_l2e, -m));
      s1[r] = __builtin_amdgcn_exp2f(__builtin_fmaf(s1[r], scale_l2e, -m));
      s2[r] = __builtin_amdgcn_exp2f(__builtin_fmaf(s2[r], scale_l2e, -m));
      s3[r] = __builtin_amdgcn_exp2f(__builtin_fmaf(s3[r], scale_l2e, -m));
    }
    {
      float sm[16];
#pragma unroll
      for (int i = 0; i < 16; i++) sm[i] = (s0[i] + s1[i]) + (s2[i] + s3[i]);
#pragma unroll
      for (int i = 0; i < 8; i++) sm[i] += sm[i + 8];
#pragma unroll
      for (int i = 0; i < 4; i++) sm[i] += sm[i + 4];
      float ps = (sm[0] + sm[1]) + (sm[2] + sm[3]);
      ps += __shfl_xor(ps, 32);
      l += ps;
    }

    // ---- O^T += V^T * P^T per 32-key group; halved-shfl exchange ----
    // lane holds P[q=lq][key = KB*32 + (r&3)+8*(r>>2)+4*hi]; B-frag needs
    // keys KB*32 + s*16 + hi*8 + j.
#define PV_KB(S, KB, OA, OB)                                                     \
  {                                                                              \
    uint w0 = pk2(S[0], S[1]), w1 = pk2(S[2], S[3]);                             \
    uint w2 = pk2(S[4], S[5]), w3 = pk2(S[6], S[7]);                             \
    uint w4 = pk2(S[8], S[9]), w5 = pk2(S[10], S[11]);                           \
    uint w6 = pk2(S[12], S[13]), w7 = pk2(S[14], S[15]);                         \
    uint r0 = (uint)__shfl_xor((int)(hi ? w0 : w2), 32);                         \
    uint r1 = (uint)__shfl_xor((int)(hi ? w1 : w3), 32);                         \
    uint r2 = (uint)__shfl_xor((int)(hi ? w4 : w6), 32);                         \
    uint r3 = (uint)__shfl_xor((int)(hi ? w5 : w7), 32);                         \
    union { uint u[4]; short8 s8; } ua, ub;                                      \
    ua.u[0] = hi ? r0 : w0; ua.u[1] = hi ? r1 : w1;                              \
    ua.u[2] = hi ? w2 : r0; ua.u[3] = hi ? w3 : r1;                              \
    ub.u[0] = hi ? r2 : w4; ub.u[1] = hi ? r3 : w5;                              \
    ub.u[2] = hi ? w6 : r2; ub.u[3] = hi ? w7 : r3;                              \
    const int c0 = (((KB) * 4 + hi) ^ (lq & 15)) << 4;                           \
    const int c1 = (((KB) * 4 + 2 + hi) ^ (lq & 15)) << 4;                       \
    short8 va0 = *(const short8*)(smem + vb_off + lq * 256 + c0);                \
    short8 va1 = *(const short8*)(smem + vb_off + (lq + 32) * 256 + c0);         \
    short8 vb0 = *(const short8*)(smem + vb_off + lq * 256 + c1);                \
    short8 vb1 = *(const short8*)(smem + vb_off + (lq + 32) * 256 + c1);         \
    __builtin_amdgcn_s_setprio(1);                                               \
    OA = __builtin_amdgcn_mfma_f32_32x32x16_bf16(va0, ua.s8, OA, 0, 0, 0);       \
    OB = __builtin_amdgcn_mfma_f32_32x32x16_bf16(va1, ua.s8, OB, 0, 0, 0);       \
    OA = __builtin_amdgcn_mfma_f32_32x32x16_bf16(vb0, ub.s8, OA, 0, 0, 0);       \
    OB = __builtin_amdgcn_mfma_f32_32x32x16_bf16(vb1, ub.s8, OB, 0, 0, 0);       \
    __builtin_amdgcn_s_setprio(0);                                               \
  }
    PV_KB(s0, 0, o0a, o1a)
    PV_KB(s1, 1, o0b, o1b)
    PV_KB(s2, 2, o0a, o1a)
    PV_KB(s3, 3, o0b, o1b)
#undef PV_KB

    if (kt < 15) {
      asm volatile("s_waitcnt vmcnt(0)" ::: "memory");  // next tile landed
      __builtin_amdgcn_s_barrier();
    }
  }
  __syncthreads();  // all waves done with K/V tiles before smem reuse

  // ---- epilogue: combine partials, 1/l, transpose via rotated LDS ----
  f32x16 o0, o1;
#pragma unroll
  for (int r = 0; r < 16; r++) { o0[r] = o0a[r] + o0b[r]; o1[r] = o1a[r] + o1b[r]; }
  float* ep = (float*)(smem) + wid * 1024;
  const float invl = 1.f / l;
  const int eq = lane >> 1, eds = lane & 1;
  float* obase = out + ((size_t)b * 2048 + qb * 256 + wid * 32 + eq) * 1024 +
                 h * 64 + eds * 16;
#pragma unroll
  for (int db = 0; db < 2; db++) {
#pragma unroll
    for (int r = 0; r < 16; r++) {
      int d = (r & 3) + 8 * (r >> 2) + 4 * hi;
      float v = (db ? o1[r] : o0[r]) * invl;
      ep[lq * 32 + ((d + lq) & 31)] = v;
    }
#pragma unroll
    for (int c = 0; c < 4; c++) {
      float4 t;
      t.x = ep[eq * 32 + ((eds * 16 + 4 * c + 0 + eq) & 31)];
      t.y = ep[eq * 32 + ((eds * 16 + 4 * c + 1 + eq) & 31)];
      t.z = ep[eq * 32 + ((eds * 16 + 4 * c + 2 + eq) & 31)];
      t.w = ep[eq * 32 + ((eds * 16 + 4 * c + 3 + eq) & 31)];
      *(float4*)(obase + db * 32 + 4 * c) = t;
    }
  }
}

// ---------------------------------------------------------------- launch
extern "C" void kernel_launch(void* const* d_in, const int* in_sizes, int n_in,
                              void* d_out, int out_size, void* d_ws, size_t ws_size,
                              hipStream_t stream) {
  (void)in_sizes; (void)n_in; (void)out_size; (void)ws_size;
  const float* src  = (const float*)d_in[0];
  const float* w    = (const float*)d_in[1];
  const float* bias = (const float*)d_in[2];
  float* out = (float*)d_out;

  char* ws = (char*)d_ws;
  bf16* src_bf = (bf16*)ws;                             // 8,388,608 B
  bf16* wt_bf  = (bf16*)(ws + 8388608);                 // 6,291,456 B
  bf16* q_ws   = (bf16*)(ws + 8388608 + 6291456);       // 32*2048*64 each
  bf16* k_ws   = q_ws + 4194304;
  bf16* vt_ws  = k_ws + 4194304;

  cvt_src_kernel<<<4096, 256, 0, stream>>>((const float4*)src, src_bf, 1048576);
  transpose_w_kernel<<<dim3(96, 32), 256, 0, stream>>>(w, wt_bf);
  qkv_gemm_kernel<<<dim3(32, 24), 256, 0, stream>>>(src_bf, wt_bf, bias, q_ws, k_ws, vt_ws);
  attn3_kernel<<<256, 512, 0, stream>>>(q_ws, k_ws, vt_ws, out);
}

// Round 7
// 100.556 us; speedup vs baseline: 1.1557x; 1.0213x over previous
//
#include <hip/hip_runtime.h>
#include <hip/hip_bf16.h>

typedef short short8 __attribute__((ext_vector_type(8)));
typedef float f32x4 __attribute__((ext_vector_type(4)));
typedef float f32x16 __attribute__((ext_vector_type(16)));
typedef __hip_bfloat16 bf16;

// Problem constants: B=2, S=2048, D=1024, H=16, HD=64, SCALE=1/8

__device__ __forceinline__ void glds16(const void* g, void* l) {
  __builtin_amdgcn_global_load_lds((const __attribute__((address_space(1))) unsigned int*)g,
                                   (__attribute__((address_space(3))) unsigned int*)l, 16, 0, 0);
}

__device__ __forceinline__ uint pk2(float a, float b) {
  union { bf16 h2[2]; uint u; } pk;
  pk.h2[0] = __float2bfloat16(a);
  pk.h2[1] = __float2bfloat16(b);
  return pk.u;
}

// ------------------------------------------------- prep: cvt src + transpose w
__global__ __launch_bounds__(256) void prep_kernel(const float4* __restrict__ in,
                                                   bf16* __restrict__ src_bf,
                                                   const float* __restrict__ w,
                                                   bf16* __restrict__ wt) {
  __shared__ float tile[32][33];
  const int bid = blockIdx.x;
  if (bid < 4096) {
    int i = bid * 256 + threadIdx.x;
    float4 v = in[i];
    union { bf16 h[4]; uint2 u; } pk;
    pk.h[0] = __float2bfloat16(v.x);
    pk.h[1] = __float2bfloat16(v.y);
    pk.h[2] = __float2bfloat16(v.z);
    pk.h[3] = __float2bfloat16(v.w);
    *(uint2*)(src_bf + (size_t)i * 4) = pk.u;
  } else {
    int id = bid - 4096;  // 0..3071
    int x0 = (id % 96) * 32;
    int y0 = (id / 96) * 32;
    int tx = threadIdx.x & 31, ty = threadIdx.x >> 5;
#pragma unroll
    for (int i = 0; i < 4; i++) {
      int y = ty + i * 8;
      tile[y][tx] = w[(size_t)(y0 + y) * 3072 + x0 + tx];
    }
    __syncthreads();
#pragma unroll
    for (int i = 0; i < 4; i++) {
      int y = ty + i * 8;
      wt[(size_t)(x0 + y) * 1024 + y0 + tx] = __float2bfloat16(tile[tx][y]);
    }
  }
}

// ------------------------------------------------------------ QKV GEMM v2 (unchanged)
__global__ __launch_bounds__(256) void qkv_gemm_kernel(
    const bf16* __restrict__ A, const bf16* __restrict__ Bt,
    const float* __restrict__ bias,
    bf16* __restrict__ q_ws, bf16* __restrict__ k_ws, bf16* __restrict__ vt_ws) {
  __shared__ alignas(16) char AB[32768];  // As [0,16K), Bs [16K,32K)
  const int tid = threadIdx.x;
  const int lane = tid & 63, wid = tid >> 6;
  const int lr = lane & 15, lg = lane >> 4;
  const int wm = wid >> 1, wn = wid & 1;
  const int m0 = blockIdx.x * 128, n0 = blockIdx.y * 128;

  const f32x4 z4 = {0.f, 0.f, 0.f, 0.f};
  f32x4 acc[4][4];
#pragma unroll
  for (int m = 0; m < 4; m++)
#pragma unroll
    for (int n = 0; n < 4; n++) acc[m][n] = z4;

  const int srow = lane >> 3;
  const int sseg = (lane & 7) ^ srow;
  const char* Ag = (const char*)A + (size_t)(m0 + wid * 32 + srow) * 2048 + sseg * 16;
  const char* Bg = (const char*)Bt + (size_t)(n0 + wid * 32 + srow) * 2048 + sseg * 16;
  char* Al = AB + wid * 4096;
  char* Bl = AB + 16384 + wid * 4096;
  const int xora = (lr & 7) << 4;

  for (int kt = 0; kt < 16; kt++) {
    __syncthreads();
#pragma unroll
    for (int c = 0; c < 4; c++) {
      glds16(Ag + (size_t)kt * 128 + c * 16384, Al + c * 1024);
      glds16(Bg + (size_t)kt * 128 + c * 16384, Bl + c * 1024);
    }
    asm volatile("s_waitcnt vmcnt(0)" ::: "memory");
    __syncthreads();
#pragma unroll
    for (int g = 0; g < 2; g++) {
      short8 af[4], bfr[4];
#pragma unroll
      for (int m = 0; m < 4; m++)
        af[m] = *(const short8*)(AB + (wm * 64 + m * 16 + lr) * 128 +
                                 ((g * 64 + lg * 16) ^ xora));
#pragma unroll
      for (int n = 0; n < 4; n++)
        bfr[n] = *(const short8*)(AB + 16384 + (wn * 64 + n * 16 + lr) * 128 +
                                  ((g * 64 + lg * 16) ^ xora));
#pragma unroll
      for (int m = 0; m < 4; m++)
#pragma unroll
        for (int n = 0; n < 4; n++)
          acc[m][n] = __builtin_amdgcn_mfma_f32_16x16x32_bf16(af[m], bfr[n], acc[m][n], 0, 0, 0);
    }
  }

  const int which = n0 >> 10;
#pragma unroll
  for (int m = 0; m < 4; m++) {
    int row = m0 + wm * 64 + m * 16 + lg * 4;
    int b = row >> 11;
    int ss0 = row & 2047;
#pragma unroll
    for (int n = 0; n < 4; n++) {
      int col = n0 + wn * 64 + n * 16 + lr;
      int d = col & 1023;
      int h = d >> 6, hd = d & 63;
      size_t bh = (size_t)(b * 16 + h);
      float bv = bias[col];
      if (which == 2) {
        union { bf16 h4[4]; uint2 u; } pk;
#pragma unroll
        for (int r = 0; r < 4; r++) pk.h4[r] = __float2bfloat16(acc[m][n][r] + bv);
        *(uint2*)&vt_ws[(bh * 64 + hd) * 2048 + ss0] = pk.u;
      } else {
        bf16* dst = (which == 0) ? q_ws : k_ws;
#pragma unroll
        for (int r = 0; r < 4; r++)
          dst[(bh * 2048 + (ss0 + r)) * 64 + hd] = __float2bfloat16(acc[m][n][r] + bv);
      }
    }
  }
}

// ------------------------------------------------------------ attention v7
// T15 cross-tile pipeline: two S-state sets (A/B). Iter t: QK(t+1)->B interleaved
// with exp2(A=tile t), sum(A), PV(A), then max(B)+rescale. K 2-buf, V 2-buf,
// staggered issue (K(t+2), V(t+1) at top), counted vmcnt, raw barriers.
#define PV_KB(S, KB)                                                           \
  {                                                                            \
    uint w0 = pk2(S[0], S[1]), w1 = pk2(S[2], S[3]);                           \
    uint w2 = pk2(S[4], S[5]), w3 = pk2(S[6], S[7]);                           \
    uint w4 = pk2(S[8], S[9]), w5 = pk2(S[10], S[11]);                         \
    uint w6 = pk2(S[12], S[13]), w7 = pk2(S[14], S[15]);                       \
    uint r0 = (uint)__shfl_xor((int)(hi ? w0 : w2), 32);                       \
    uint r1 = (uint)__shfl_xor((int)(hi ? w1 : w3), 32);                       \
    uint r2 = (uint)__shfl_xor((int)(hi ? w4 : w6), 32);                       \
    uint r3 = (uint)__shfl_xor((int)(hi ? w5 : w7), 32);                       \
    union { uint u[4]; short8 s8; } ua, ub;                                    \
    ua.u[0] = hi ? r0 : w0; ua.u[1] = hi ? r1 : w1;                            \
    ua.u[2] = hi ? w2 : r0; ua.u[3] = hi ? w3 : r1;                            \
    ub.u[0] = hi ? r2 : w4; ub.u[1] = hi ? r3 : w5;                            \
    ub.u[2] = hi ? w6 : r2; ub.u[3] = hi ? w7 : r3;                            \
    const int c0 = (((KB) * 4 + hi) ^ (lq & 15)) << 4;                         \
    const int c1 = (((KB) * 4 + 2 + hi) ^ (lq & 15)) << 4;                     \
    short8 va0 = *(const short8*)(smem + vbc + lq * 256 + c0);                 \
    short8 va1 = *(const short8*)(smem + vbc + (lq + 32) * 256 + c0);          \
    short8 vb0 = *(const short8*)(smem + vbc + lq * 256 + c1);                 \
    short8 vb1 = *(const short8*)(smem + vbc + (lq + 32) * 256 + c1);          \
    __builtin_amdgcn_s_setprio(1);                                             \
    o0 = __builtin_amdgcn_mfma_f32_32x32x16_bf16(va0, ua.s8, o0, 0, 0, 0);     \
    o1 = __builtin_amdgcn_mfma_f32_32x32x16_bf16(va1, ua.s8, o1, 0, 0, 0);     \
    o0 = __builtin_amdgcn_mfma_f32_32x32x16_bf16(vb0, ub.s8, o0, 0, 0, 0);     \
    o1 = __builtin_amdgcn_mfma_f32_32x32x16_bf16(vb1, ub.s8, o1, 0, 0, 0);     \
    __builtin_amdgcn_s_setprio(0);                                             \
  }

#define QK_ST(ST, AR, B0, B1, B2, B3, QKF, KBN)                                \
  {                                                                            \
    if (QKF) {                                                                 \
      const int doff = ((ST) * 32 + hi16) ^ xorv;                              \
      short8 ka = *(const short8*)(smem + (KBN) + lq * 128 + doff);            \
      short8 kb = *(const short8*)(smem + (KBN) + (lq + 32) * 128 + doff);     \
      short8 kc = *(const short8*)(smem + (KBN) + (lq + 64) * 128 + doff);     \
      short8 kd = *(const short8*)(smem + (KBN) + (lq + 96) * 128 + doff);     \
      __builtin_amdgcn_s_setprio(1);                                           \
      B0 = __builtin_amdgcn_mfma_f32_32x32x16_bf16(ka, qf[ST], B0, 0, 0, 0);   \
      B1 = __builtin_amdgcn_mfma_f32_32x32x16_bf16(kb, qf[ST], B1, 0, 0, 0);   \
      B2 = __builtin_amdgcn_mfma_f32_32x32x16_bf16(kc, qf[ST], B2, 0, 0, 0);   \
      B3 = __builtin_amdgcn_mfma_f32_32x32x16_bf16(kd, qf[ST], B3, 0, 0, 0);   \
      __builtin_amdgcn_s_setprio(0);                                           \
    }                                                                          \
    _Pragma("unroll")                                                          \
    for (int r_ = 0; r_ < 16; r_++)                                            \
      AR[r_] = __builtin_amdgcn_exp2f(__builtin_fmaf(AR[r_], scale_l2e, -m));  \
  }

#define ATTN_ITER(T, A0, A1, A2, A3, B0, B1, B2, B3, VMC, KF, VF, QKF, EB)     \
  {                                                                            \
    if (KF) {                                                                  \
      glds16(kgl + (size_t)((T) + 2) * 16384,                                  \
             smem + ((T) & 1) * 16384 + wid * 2048);                           \
      glds16(kgl + (size_t)((T) + 2) * 16384 + 1024,                           \
             smem + ((T) & 1) * 16384 + wid * 2048 + 1024);                    \
    }                                                                          \
    if (VF) {                                                                  \
      glds16(vg0 + (size_t)((T) + 1) * 256,                                    \
             smem + 32768 + (((T) + 1) & 1) * 16384 + wid * 2048);             \
      glds16(vg1 + (size_t)((T) + 1) * 256,                                    \
             smem + 32768 + (((T) + 1) & 1) * 16384 + wid * 2048 + 1024);      \
    }                                                                          \
    asm volatile("s_waitcnt vmcnt(" #VMC ")" ::: "memory");                    \
    __builtin_amdgcn_s_barrier();                                              \
    const int kbn = (((T) + 1) & 1) * 16384;                                   \
    const int vbc = 32768 + ((T) & 1) * 16384;                                 \
    if (QKF) {                                                                 \
      _Pragma("unroll") for (int r_ = 0; r_ < 16; r_++) {                      \
        B0[r_] = 0.f; B1[r_] = 0.f; B2[r_] = 0.f; B3[r_] = 0.f;                \
      }                                                                        \
    }                                                                          \
    QK_ST(0, A0, B0, B1, B2, B3, QKF, kbn)                                     \
    QK_ST(1, A1, B0, B1, B2, B3, QKF, kbn)                                     \
    QK_ST(2, A2, B0, B1, B2, B3, QKF, kbn)                                     \
    QK_ST(3, A3, B0, B1, B2, B3, QKF, kbn)                                     \
    {                                                                          \
      float sm_[16];                                                           \
      _Pragma("unroll") for (int i = 0; i < 16; i++)                           \
        sm_[i] = (A0[i] + A1[i]) + (A2[i] + A3[i]);                            \
      _Pragma("unroll") for (int i = 0; i < 8; i++) sm_[i] += sm_[i + 8];      \
      _Pragma("unroll") for (int i = 0; i < 4; i++) sm_[i] += sm_[i + 4];      \
      float ps = (sm_[0] + sm_[1]) + (sm_[2] + sm_[3]);                        \
      ps += __shfl_xor(ps, 32);                                                \
      l += ps;                                                                 \
    }                                                                          \
    PV_KB(A0, 0)                                                               \
    PV_KB(A1, 1)                                                               \
    PV_KB(A2, 2)                                                               \
    PV_KB(A3, 3)                                                               \
    if (QKF) {                                                                 \
      float mx_[16];                                                           \
      _Pragma("unroll") for (int i = 0; i < 16; i++)                           \
        mx_[i] = fmaxf(fmaxf(B0[i], B1[i]), fmaxf(B2[i], B3[i]));              \
      _Pragma("unroll") for (int i = 0; i < 8; i++)                            \
        mx_[i] = fmaxf(mx_[i], mx_[i + 8]);                                    \
      _Pragma("unroll") for (int i = 0; i < 4; i++)                            \
        mx_[i] = fmaxf(mx_[i], mx_[i + 4]);                                    \
      float pm = fmaxf(fmaxf(mx_[0], mx_[1]), fmaxf(mx_[2], mx_[3]));          \
      pm = fmaxf(pm, __shfl_xor(pm, 32));                                      \
      pm *= scale_l2e;                                                         \
      if (pm > m + 8.f) {                                                      \
        float rs = __builtin_amdgcn_exp2f(m - pm);                             \
        m = pm;                                                                \
        l *= rs;                                                               \
        _Pragma("unroll") for (int r_ = 0; r_ < 16; r_++) {                    \
          o0[r_] *= rs;                                                        \
          o1[r_] *= rs;                                                        \
        }                                                                      \
      }                                                                        \
    }                                                                          \
    if (EB) __builtin_amdgcn_s_barrier();                                      \
  }

__global__ __launch_bounds__(512, 2) void attn4_kernel(
    const bf16* __restrict__ q_ws, const bf16* __restrict__ k_ws,
    const bf16* __restrict__ vt_ws, float* __restrict__ out) {
  // [0,32K): K bufs [2][128][64] bf16 (row&7 xor-swz); [32K,64K): V^T bufs
  // [2][64][128] bf16 (256B rows, chunk ^ (d&15) swz)
  __shared__ alignas(16) char smem[65536];
  const int tid = threadIdx.x;
  const int lane = tid & 63, wid = tid >> 6;
  const int lq = lane & 31, hi = lane >> 5;
  const int hi16 = hi * 16;
  const int xorv = (lq & 7) << 4;
  const float scale_l2e = 0.125f * 1.44269504088896f;

  const int f = blockIdx.x;
  const int bh = (f & 7) * 4 + ((f >> 3) & 3);
  const int qb = f >> 5;
  const int b = bh >> 4, h = bh & 15;
  const int q0 = qb * 256 + wid * 32;

  short8 qf[4];
  {
    const bf16* qrow = q_ws + ((size_t)bh * 2048 + q0 + lq) * 64;
#pragma unroll
    for (int s = 0; s < 4; s++) qf[s] = *(const short8*)(qrow + s * 16 + hi * 8);
  }

  const int l8 = lane >> 3;
  const int segk = (lane & 7) ^ l8;
  const char* kgl = (const char*)k_ws + (size_t)bh * 262144 +
                    (size_t)(wid * 16 + l8) * 128 + segk * 16;
  const int l16 = lane >> 4;
  const int d0v = wid * 8 + l16;
  const int d1v = wid * 8 + 4 + l16;
  const char* vg0 = (const char*)vt_ws + (size_t)bh * 262144 + (size_t)d0v * 4096 +
                    (((lane & 15) ^ (d0v & 15)) << 4);
  const char* vg1 = (const char*)vt_ws + (size_t)bh * 262144 + (size_t)d1v * 4096 +
                    (((lane & 15) ^ (d1v & 15)) << 4);
  char* kl0 = smem + wid * 2048;
  char* vl0 = smem + 32768 + wid * 2048;

  f32x16 o0, o1, a0, a1, a2, a3, b0, b1, b2, b3;
#pragma unroll
  for (int r = 0; r < 16; r++) { o0[r] = 0.f; o1[r] = 0.f; }
  float m = -1e30f, l = 0.f;

  // ---- prologue: issue K(0),K(1),V(0); compute QK(0)->A; max(A)->m ----
  glds16(kgl, kl0);
  glds16(kgl + 1024, kl0 + 1024);
  glds16(kgl + 16384, kl0 + 16384);
  glds16(kgl + 16384 + 1024, kl0 + 16384 + 1024);
  glds16(vg0, vl0);
  glds16(vg1, vl0 + 1024);
  asm volatile("s_waitcnt vmcnt(4)" ::: "memory");  // K(0) landed
  __builtin_amdgcn_s_barrier();
#pragma unroll
  for (int r = 0; r < 16; r++) { a0[r] = 0.f; a1[r] = 0.f; a2[r] = 0.f; a3[r] = 0.f; }
#pragma unroll
  for (int st = 0; st < 4; st++) {
    const int doff = (st * 32 + hi16) ^ xorv;
    short8 ka = *(const short8*)(smem + lq * 128 + doff);
    short8 kb = *(const short8*)(smem + (lq + 32) * 128 + doff);
    short8 kc = *(const short8*)(smem + (lq + 64) * 128 + doff);
    short8 kd = *(const short8*)(smem + (lq + 96) * 128 + doff);
    __builtin_amdgcn_s_setprio(1);
    a0 = __builtin_amdgcn_mfma_f32_32x32x16_bf16(ka, qf[st], a0, 0, 0, 0);
    a1 = __builtin_amdgcn_mfma_f32_32x32x16_bf16(kb, qf[st], a1, 0, 0, 0);
    a2 = __builtin_amdgcn_mfma_f32_32x32x16_bf16(kc, qf[st], a2, 0, 0, 0);
    a3 = __builtin_amdgcn_mfma_f32_32x32x16_bf16(kd, qf[st], a3, 0, 0, 0);
    __builtin_amdgcn_s_setprio(0);
  }
  {
    float mx_[16];
#pragma unroll
    for (int i = 0; i < 16; i++)
      mx_[i] = fmaxf(fmaxf(a0[i], a1[i]), fmaxf(a2[i], a3[i]));
#pragma unroll
    for (int i = 0; i < 8; i++) mx_[i] = fmaxf(mx_[i], mx_[i + 8]);
#pragma unroll
    for (int i = 0; i < 4; i++) mx_[i] = fmaxf(mx_[i], mx_[i + 4]);
    float pm = fmaxf(fmaxf(mx_[0], mx_[1]), fmaxf(mx_[2], mx_[3]));
    pm = fmaxf(pm, __shfl_xor(pm, 32));
    pm *= scale_l2e;
    m = pm;  // o==0, l==0: plain assign
  }
  __builtin_amdgcn_s_barrier();  // all waves done reading K(0) before iter0 overwrites

  // ---- steady: iters 0..13 (2x unrolled, A/B swap) ----
  for (int tt = 0; tt < 7; ++tt) {
    const int T0 = 2 * tt;
    const int T1 = 2 * tt + 1;
    ATTN_ITER(T0, a0, a1, a2, a3, b0, b1, b2, b3, 4, 1, 1, 1, 1)
    ATTN_ITER(T1, b0, b1, b2, b3, a0, a1, a2, a3, 4, 1, 1, 1, 1)
  }
  // ---- tail: iter 14 (no K issue), iter 15 (finish only) ----
  ATTN_ITER(14, a0, a1, a2, a3, b0, b1, b2, b3, 2, 0, 1, 1, 1)
  ATTN_ITER(15, b0, b1, b2, b3, a0, a1, a2, a3, 0, 0, 0, 0, 0)

  __syncthreads();  // drain before smem reuse

  // ---- epilogue: 1/l, transpose O^T->O via rotated LDS ----
  float* ep = (float*)(smem) + wid * 1024;
  const float invl = 1.f / l;
  const int eq = lane >> 1, eds = lane & 1;
  float* obase = out + ((size_t)b * 2048 + qb * 256 + wid * 32 + eq) * 1024 +
                 h * 64 + eds * 16;
#pragma unroll
  for (int db = 0; db < 2; db++) {
#pragma unroll
    for (int r = 0; r < 16; r++) {
      int d = (r & 3) + 8 * (r >> 2) + 4 * hi;
      float v = (db ? o1[r] : o0[r]) * invl;
      ep[lq * 32 + ((d + lq) & 31)] = v;
    }
#pragma unroll
    for (int c = 0; c < 4; c++) {
      float4 t;
      t.x = ep[eq * 32 + ((eds * 16 + 4 * c + 0 + eq) & 31)];
      t.y = ep[eq * 32 + ((eds * 16 + 4 * c + 1 + eq) & 31)];
      t.z = ep[eq * 32 + ((eds * 16 + 4 * c + 2 + eq) & 31)];
      t.w = ep[eq * 32 + ((eds * 16 + 4 * c + 3 + eq) & 31)];
      *(float4*)(obase + db * 32 + 4 * c) = t;
    }
  }
}

// ---------------------------------------------------------------- launch
extern "C" void kernel_launch(void* const* d_in, const int* in_sizes, int n_in,
                              void* d_out, int out_size, void* d_ws, size_t ws_size,
                              hipStream_t stream) {
  (void)in_sizes; (void)n_in; (void)out_size; (void)ws_size;
  const float* src  = (const float*)d_in[0];
  const float* w    = (const float*)d_in[1];
  const float* bias = (const float*)d_in[2];
  float* out = (float*)d_out;

  char* ws = (char*)d_ws;
  bf16* src_bf = (bf16*)ws;                             // 8,388,608 B
  bf16* wt_bf  = (bf16*)(ws + 8388608);                 // 6,291,456 B
  bf16* q_ws   = (bf16*)(ws + 8388608 + 6291456);       // 32*2048*64 each
  bf16* k_ws   = q_ws + 4194304;
  bf16* vt_ws  = k_ws + 4194304;

  prep_kernel<<<7168, 256, 0, stream>>>((const float4*)src, src_bf, w, wt_bf);
  qkv_gemm_kernel<<<dim3(32, 24), 256, 0, stream>>>(src_bf, wt_bf, bias, q_ws, k_ws, vt_ws);
  attn4_kernel<<<256, 512, 0, stream>>>(q_ws, k_ws, vt_ws, out);
}